// Round 1
// baseline (5017.095 us; speedup 1.0000x reference)
//
#include <hip/hip_runtime.h>
#include <hip/hip_bf16.h>

// GRU-D fused scan: one block per batch element (256 blocks = 1/CU), 384 threads
// (thread g owns gate-row g of all 4 weight matrices, packed f16 in registers,
// ~209 VGPRs). Hidden state packed f16 in LDS, broadcast ds_read_b128 in dots.
// Imputation (NaN forward-fill + time delta) fused: wave 0 keeps running state,
// x[t+1] prefetched during dot phase. 3 barriers/step.

#define BB 256
#define SS 1024
#define DD 32
#define HH 128
#define IN_DIM 34
#define NT 384

typedef _Float16 f16;
typedef __attribute__((ext_vector_type(2))) _Float16 h2;
typedef __attribute__((ext_vector_type(8))) _Float16 h8;

union H8v { h8 v; h2 p[4]; };

__device__ inline float dot2(h2 a, h2 b, float c) {
#if __has_builtin(__builtin_amdgcn_fdot2)
    return __builtin_amdgcn_fdot2(a, b, c, false);
#else
    return c + (float)a.x * (float)b.x + (float)a.y * (float)b.y;
#endif
}

__device__ inline float frcp(float x) {
#if __has_builtin(__builtin_amdgcn_rcpf)
    return __builtin_amdgcn_rcpf(x);
#else
    return 1.0f / x;
#endif
}

__device__ inline float fast_sigm(float x) {
    return frcp(1.0f + __expf(-x));
}

__device__ inline float fast_tanh(float x) {
    x = fminf(15.0f, fmaxf(-15.0f, x));
    float e = __expf(-2.0f * x);
    return (1.0f - e) * frcp(1.0f + e);
}

struct ImpState { float xprev, tprev; bool hasprev; };

// Executed by wave 0 only (g < 64), wave-uniform control flow (ballot inside).
__device__ inline void impute_step(int i, float xv, int g, ImpState& st,
                                   f16* hx, const float* tb) {
    bool nanp = (g < 32) && (xv != xv);
    unsigned long long bal = __ballot(nanp);
    bool mask = bal != 0ull;
    if (g < 32) {
        float imp = mask ? st.xprev : xv;
        hx[g] = (f16)imp;
        if (!mask) st.xprev = xv;
    } else if (g == 32) {
        hx[32] = (f16)(mask ? 1.0f : 0.0f);
    }
    float tcur = tb[i];
    float tdel = (i == 0) ? 0.0f : (tcur - tb[i - 1]);
    float texp = st.hasprev ? (tcur - st.tprev) : tdel;
    if (g == 33) hx[33] = (f16)texp;
    if (!mask) { st.hasprev = true; st.tprev = tcur; }
}

__global__ __launch_bounds__(NT, 2) void gru_fused(
    const float* __restrict__ t_in, const float* __restrict__ x_in,
    const float* __restrict__ Wih0, const float* __restrict__ Whh0,
    const float* __restrict__ bih0, const float* __restrict__ bhh0,
    const float* __restrict__ Wih1, const float* __restrict__ Whh1,
    const float* __restrict__ bih1, const float* __restrict__ bhh1,
    float* __restrict__ out)
{
    __shared__ float tb[SS];                 // timestamps (shared across batch)
    __shared__ h8 hxs[5];                    // imputed input vec, 40 halves (34 used)
    __shared__ h8 h0s[16];                   // h0 packed f16 (128)
    __shared__ h8 h1s[16];                   // h1 packed f16 (128)
    __shared__ float rz0[256];               // r,z gates layer 0
    __shared__ float rz1[256];               // r,z gates layer 1

    const int g = threadIdx.x;
    const int b = blockIdx.x;

    // ---- load + pack weights into registers (f32 -> f16x2) ----
    h2 wih0[17], whh0[64], wih1[64], whh1[64];
    {
        const float* p = Wih0 + g * IN_DIM;
        #pragma unroll
        for (int k = 0; k < 17; k++) { h2 v = {(f16)p[2*k], (f16)p[2*k+1]}; wih0[k] = v; }
        p = Whh0 + g * HH;
        #pragma unroll
        for (int k = 0; k < 64; k++) { h2 v = {(f16)p[2*k], (f16)p[2*k+1]}; whh0[k] = v; }
        p = Wih1 + g * HH;
        #pragma unroll
        for (int k = 0; k < 64; k++) { h2 v = {(f16)p[2*k], (f16)p[2*k+1]}; wih1[k] = v; }
        p = Whh1 + g * HH;
        #pragma unroll
        for (int k = 0; k < 64; k++) { h2 v = {(f16)p[2*k], (f16)p[2*k+1]}; whh1[k] = v; }
    }
    const float bi0 = bih0[g], bh0 = bhh0[g], bi1 = bih1[g], bh1 = bhh1[g];

    for (int i = g; i < SS; i += NT) tb[i] = t_in[i];
    f16* hx = (f16*)hxs;
    if (g >= 34 && g < 40) hx[g] = (f16)0.0f;          // pad region
    if (g < 128) { ((f16*)h0s)[g] = (f16)0.0f; ((f16*)h1s)[g] = (f16)0.0f; }
    float h0r = 0.0f, h1r = 0.0f;

    const float* xrow = x_in + (size_t)b * SS * DD + g;  // valid deref only g<32
    ImpState st; st.xprev = 0.0f; st.tprev = 0.0f; st.hasprev = false;

    __syncthreads();
    if (g < 64) {
        float xv0 = (g < 32) ? xrow[0] : 0.0f;
        impute_step(0, xv0, g, st, hx, tb);
    }
    __syncthreads();

    const h8* hx8 = (const h8*)hxs;
    const h8* h08 = (const h8*)h0s;
    const h8* h18 = (const h8*)h1s;
    const h2* hx2 = (const h2*)hxs;

    for (int tt = 0; tt < SS; ++tt) {
        // prefetch next x row (consumed after B_b in impute)
        float xv_n = 0.0f;
        if (g < 32) xv_n = xrow[(size_t)((tt + 1 < SS) ? (tt + 1) : (SS - 1)) * DD];

        // ---- layer 0 dots: gx over hx (17 h2), gh over h0 (64 h2) ----
        float a0 = 0, a1 = 0, a2 = 0, a3 = 0;
        #pragma unroll
        for (int q = 0; q < 4; q++) {
            H8v u; u.v = hx8[q];
            a0 = dot2(u.p[0], wih0[4*q+0], a0);
            a1 = dot2(u.p[1], wih0[4*q+1], a1);
            a2 = dot2(u.p[2], wih0[4*q+2], a2);
            a3 = dot2(u.p[3], wih0[4*q+3], a3);
        }
        a0 = dot2(hx2[16], wih0[16], a0);
        float gx = bi0 + ((a0 + a1) + (a2 + a3));
        float c0 = 0, c1 = 0, c2 = 0, c3 = 0;
        #pragma unroll
        for (int q = 0; q < 16; q++) {
            H8v u; u.v = h08[q];
            c0 = dot2(u.p[0], whh0[4*q+0], c0);
            c1 = dot2(u.p[1], whh0[4*q+1], c1);
            c2 = dot2(u.p[2], whh0[4*q+2], c2);
            c3 = dot2(u.p[3], whh0[4*q+3], c3);
        }
        float gh = bh0 + ((c0 + c1) + (c2 + c3));
        if (g < 256) rz0[g] = fast_sigm(gx + gh);
        __syncthreads();   // B_b

        if (g >= 256) {    // layer-0 h update (thread owns hidden unit j)
            int j = g - 256;
            float r = rz0[j], z = rz0[128 + j];
            float n = fast_tanh(gx + r * gh);
            h0r = (1.0f - z) * n + z * h0r;
            ((f16*)h0s)[j] = (f16)h0r;
        } else if (g < 64) {  // impute next step concurrently
            int i = tt + 1;
            if (i < SS) impute_step(i, xv_n, g, st, hx, tb);
        }
        __syncthreads();   // B_c

        // ---- layer 1 dots: gx1 over h0 (updated), gh1 over h1 ----
        float d0 = 0, d1 = 0, d2 = 0, d3 = 0;
        #pragma unroll
        for (int q = 0; q < 16; q++) {
            H8v u; u.v = h08[q];
            d0 = dot2(u.p[0], wih1[4*q+0], d0);
            d1 = dot2(u.p[1], wih1[4*q+1], d1);
            d2 = dot2(u.p[2], wih1[4*q+2], d2);
            d3 = dot2(u.p[3], wih1[4*q+3], d3);
        }
        float e0 = 0, e1 = 0, e2 = 0, e3 = 0;
        #pragma unroll
        for (int q = 0; q < 16; q++) {
            H8v u; u.v = h18[q];
            e0 = dot2(u.p[0], whh1[4*q+0], e0);
            e1 = dot2(u.p[1], whh1[4*q+1], e1);
            e2 = dot2(u.p[2], whh1[4*q+2], e2);
            e3 = dot2(u.p[3], whh1[4*q+3], e3);
        }
        float gx1 = bi1 + ((d0 + d1) + (d2 + d3));
        float gh1 = bh1 + ((e0 + e1) + (e2 + e3));
        if (g < 256) rz1[g] = fast_sigm(gx1 + gh1);
        __syncthreads();   // B_d

        if (g >= 256) {    // layer-1 h update
            int j = g - 256;
            float r = rz1[j], z = rz1[128 + j];
            float n = fast_tanh(gx1 + r * gh1);
            h1r = (1.0f - z) * n + z * h1r;
            ((f16*)h1s)[j] = (f16)h1r;
        }
        // loop-around barrier elided: rz buffers are per-layer, h writes are
        // separated from next readers by >=2 barriers (ordering verified).
    }

    if (g >= 256) out[(size_t)b * HH + (g - 256)] = h1r;
}

extern "C" void kernel_launch(void* const* d_in, const int* in_sizes, int n_in,
                              void* d_out, int out_size, void* d_ws, size_t ws_size,
                              hipStream_t stream) {
    gru_fused<<<dim3(BB), dim3(NT), 0, stream>>>(
        (const float*)d_in[0], (const float*)d_in[1],
        (const float*)d_in[2], (const float*)d_in[3],
        (const float*)d_in[4], (const float*)d_in[5],
        (const float*)d_in[6], (const float*)d_in[7],
        (const float*)d_in[8], (const float*)d_in[9],
        (float*)d_out);
}

// Round 2
// 1811.050 us; speedup vs baseline: 2.7703x; 2.7703x over previous
//
#include <hip/hip_runtime.h>
#include <hip/hip_bf16.h>

// GRU-D fused scan, K-split edition.
// One block per batch element (256 blocks = 1 per CU). 768 threads:
// lane pair (g = tid>>1, half = tid&1); thread owns gate-row g, K-half `half`
// of all 4 weight matrices packed f16 in registers (105 h2 ~= 105 VGPRs,
// fits the 170-reg cap required for a 12-wave block at 3 waves/SIMD).
// Partial dots combined via __shfl_xor(.,1) (adjacent lanes, same wave).
// Hidden state packed f16 in LDS, broadcast reads (2 addrs/wave = free).
// Imputation fused in wave 0 between barriers. 3 barriers/step.

#define BB 256
#define SS 1024
#define DD 32
#define HH 128
#define NT 768

typedef _Float16 f16;
typedef __attribute__((ext_vector_type(2))) _Float16 h2;
typedef __attribute__((ext_vector_type(8))) _Float16 h8;

union H8v { h8 v; h2 p[4]; };

__device__ inline float dot2(h2 a, h2 b, float c) {
#if __has_builtin(__builtin_amdgcn_fdot2)
    return __builtin_amdgcn_fdot2(a, b, c, false);
#else
    return c + (float)a.x * (float)b.x + (float)a.y * (float)b.y;
#endif
}

__device__ inline float frcp(float x) {
#if __has_builtin(__builtin_amdgcn_rcpf)
    return __builtin_amdgcn_rcpf(x);
#else
    return 1.0f / x;
#endif
}

__device__ inline float fast_sigm(float x) {
    return frcp(1.0f + __expf(-x));
}

__device__ inline float fast_tanh(float x) {
    x = fminf(15.0f, fmaxf(-15.0f, x));
    float e = __expf(-2.0f * x);
    return (1.0f - e) * frcp(1.0f + e);
}

struct ImpState { float xprev, tprev; bool hasprev; };

// Executed by wave 0 only (tid < 64): g = tid>>1 in [0,32), half = tid&1.
// half==0 lanes carry per-feature xprev; t-state is wave-uniform.
__device__ inline void impute_step(int i, float xv, int tid, ImpState& st,
                                   f16* hx, const float* tb) {
    int g = tid >> 1;
    bool nanp = ((tid & 1) == 0) && (xv != xv);
    unsigned long long bal = __ballot(nanp);
    bool mask = bal != 0ull;
    if ((tid & 1) == 0) {
        float imp = mask ? st.xprev : xv;
        hx[g] = (f16)imp;
        if (!mask) st.xprev = xv;
    }
    float tcur = tb[i];
    float tdel = (i == 0) ? 0.0f : (tcur - tb[i - 1]);
    float texp = st.hasprev ? (tcur - st.tprev) : tdel;
    if (tid == 1) hx[32] = (f16)(mask ? 1.0f : 0.0f);
    if (tid == 3) hx[33] = (f16)texp;
    if (!mask) { st.hasprev = true; st.tprev = tcur; }
}

__global__ __launch_bounds__(NT, 3) void gru_fused(
    const float* __restrict__ t_in, const float* __restrict__ x_in,
    const float* __restrict__ Wih0, const float* __restrict__ Whh0,
    const float* __restrict__ bih0, const float* __restrict__ bhh0,
    const float* __restrict__ Wih1, const float* __restrict__ Whh1,
    const float* __restrict__ bih1, const float* __restrict__ bhh1,
    float* __restrict__ out)
{
    __shared__ float tb[SS];      // timestamps (shared across batch)
    __shared__ h8 hxs[5];         // imputed input, 40 f16 (34 used: x|mask|texp)
    __shared__ h8 h0s[16];        // h0 packed f16 (128)
    __shared__ h8 h1s[16];        // h1 packed f16 (128)
    __shared__ float rz0[256];    // r,z gates layer 0
    __shared__ float rz1[256];    // r,z gates layer 1

    const int tid = threadIdx.x;
    const int g = tid >> 1;       // gate row 0..383
    const int half = tid & 1;     // K half
    const int b = blockIdx.x;

    // ---- load + pack this thread's half-row of each matrix (f32 -> f16x2) ----
    // Wih0 (34-dim rows): half0 covers elems [0,16), half1 [16,34).
    // 9-iteration uniform loop; half0's 9th term is zero-padded.
    h2 wih0[9], whh0[32], wih1[32], whh1[32];
    {
        const float* p = Wih0 + g * 34;
        const int lim = 8 + half;               // half0: 8 terms, half1: 9
        #pragma unroll
        for (int k = 0; k < 9; k++) {
            int e = 16 * half + 2 * k;
            f16 lo = (k < lim) ? (f16)p[e]     : (f16)0.0f;
            f16 hi = (k < lim) ? (f16)p[e + 1] : (f16)0.0f;
            h2 v = {lo, hi}; wih0[k] = v;
        }
        p = Whh0 + g * HH + 64 * half;
        #pragma unroll
        for (int k = 0; k < 32; k++) { h2 v = {(f16)p[2*k], (f16)p[2*k+1]}; whh0[k] = v; }
        p = Wih1 + g * HH + 64 * half;
        #pragma unroll
        for (int k = 0; k < 32; k++) { h2 v = {(f16)p[2*k], (f16)p[2*k+1]}; wih1[k] = v; }
        p = Whh1 + g * HH + 64 * half;
        #pragma unroll
        for (int k = 0; k < 32; k++) { h2 v = {(f16)p[2*k], (f16)p[2*k+1]}; whh1[k] = v; }
    }
    const float bi0 = bih0[g], bh0 = bhh0[g], bi1 = bih1[g], bh1 = bhh1[g];

    for (int i = tid; i < SS; i += NT) tb[i] = t_in[i];
    f16* hx = (f16*)hxs;
    if (tid >= 34 && tid < 40) hx[tid] = (f16)0.0f;           // pad
    if (tid < 128) { ((f16*)h0s)[tid] = (f16)0.0f; ((f16*)h1s)[tid] = (f16)0.0f; }
    float h0r = 0.0f, h1r = 0.0f;

    const float* xrow = x_in + (size_t)b * SS * DD + g;  // deref only tid<64 even
    ImpState st; st.xprev = 0.0f; st.tprev = 0.0f; st.hasprev = false;

    __syncthreads();
    if (tid < 64) {
        float xv0 = ((tid & 1) == 0) ? xrow[0] : 0.0f;
        impute_step(0, xv0, tid, st, hx, tb);
    }
    __syncthreads();

    const h2* hx2 = (const h2*)hxs;
    const h8* h08 = (const h8*)h0s;
    const h8* h18 = (const h8*)h1s;

    for (int tt = 0; tt < SS; ++tt) {
        // prefetch next x row (consumed in impute after B_b)
        float xv_n = 0.0f;
        if (tid < 64 && (tid & 1) == 0)
            xv_n = xrow[(size_t)((tt + 1 < SS) ? (tt + 1) : (SS - 1)) * DD];

        // ---- layer 0 partial dots over this K-half ----
        float a0 = 0.0f;
        #pragma unroll
        for (int k = 0; k < 9; k++) a0 = dot2(hx2[8 * half + k], wih0[k], a0);
        float c0 = 0, c1 = 0, c2 = 0, c3 = 0;
        #pragma unroll
        for (int q = 0; q < 8; q++) {
            H8v u; u.v = h08[8 * half + q];
            c0 = dot2(u.p[0], whh0[4*q+0], c0);
            c1 = dot2(u.p[1], whh0[4*q+1], c1);
            c2 = dot2(u.p[2], whh0[4*q+2], c2);
            c3 = dot2(u.p[3], whh0[4*q+3], c3);
        }
        float ghp = (c0 + c1) + (c2 + c3);
        float gx = bi0 + a0  + __shfl_xor(a0, 1);
        float gh = bh0 + ghp + __shfl_xor(ghp, 1);
        if (g < 256 && half == 0) rz0[g] = fast_sigm(gx + gh);
        __syncthreads();   // B_b

        if (tid >= 512) {           // layer-0 h update (row pair owns unit j)
            int j = g - 256;
            float r = rz0[j], z = rz0[128 + j];
            float n = fast_tanh(gx + r * gh);
            h0r = (1.0f - z) * n + z * h0r;
            if (half == 0) ((f16*)h0s)[j] = (f16)h0r;
        } else if (tid < 64) {      // impute next step concurrently
            if (tt + 1 < SS) impute_step(tt + 1, xv_n, tid, st, hx, tb);
        }
        __syncthreads();   // B_c

        // ---- layer 1 partial dots: gx1 over updated h0, gh1 over h1 ----
        float d0 = 0, d1 = 0, d2 = 0, d3 = 0;
        #pragma unroll
        for (int q = 0; q < 8; q++) {
            H8v u; u.v = h08[8 * half + q];
            d0 = dot2(u.p[0], wih1[4*q+0], d0);
            d1 = dot2(u.p[1], wih1[4*q+1], d1);
            d2 = dot2(u.p[2], wih1[4*q+2], d2);
            d3 = dot2(u.p[3], wih1[4*q+3], d3);
        }
        float e0 = 0, e1 = 0, e2 = 0, e3 = 0;
        #pragma unroll
        for (int q = 0; q < 8; q++) {
            H8v u; u.v = h18[8 * half + q];
            e0 = dot2(u.p[0], whh1[4*q+0], e0);
            e1 = dot2(u.p[1], whh1[4*q+1], e1);
            e2 = dot2(u.p[2], whh1[4*q+2], e2);
            e3 = dot2(u.p[3], whh1[4*q+3], e3);
        }
        float dxp = (d0 + d1) + (d2 + d3);
        float ehp = (e0 + e1) + (e2 + e3);
        float gx1 = bi1 + dxp + __shfl_xor(dxp, 1);
        float gh1 = bh1 + ehp + __shfl_xor(ehp, 1);
        if (g < 256 && half == 0) rz1[g] = fast_sigm(gx1 + gh1);
        __syncthreads();   // B_d

        if (tid >= 512) {           // layer-1 h update
            int j = g - 256;
            float r = rz1[j], z = rz1[128 + j];
            float n = fast_tanh(gx1 + r * gh1);
            h1r = (1.0f - z) * n + z * h1r;
            if (half == 0) ((f16*)h1s)[j] = (f16)h1r;
        }
        // loop-around barrier elided: every LDS buffer's read phase and its
        // next write phase are separated by >=1 intervening barrier (checked
        // per-buffer: rz0/rz1/h0s/h1s/hx).
    }

    if (tid >= 512 && half == 0) out[(size_t)b * HH + (g - 256)] = h1r;
}

extern "C" void kernel_launch(void* const* d_in, const int* in_sizes, int n_in,
                              void* d_out, int out_size, void* d_ws, size_t ws_size,
                              hipStream_t stream) {
    gru_fused<<<dim3(BB), dim3(NT), 0, stream>>>(
        (const float*)d_in[0], (const float*)d_in[1],
        (const float*)d_in[2], (const float*)d_in[3],
        (const float*)d_in[4], (const float*)d_in[5],
        (const float*)d_in[6], (const float*)d_in[7],
        (const float*)d_in[8], (const float*)d_in[9],
        (float*)d_out);
}

// Round 3
// 1685.165 us; speedup vs baseline: 2.9772x; 1.0747x over previous
//
#include <hip/hip_runtime.h>
#include <hip/hip_bf16.h>

// GRU-D fused scan, K-split + LDS-streamed Whh1.
// One block per batch element (256 blocks = 1 per CU). 768 threads:
// lane pair (g = tid>>1, half = tid&1); thread owns gate-row g, K-half `half`.
// Wih0/Whh0/Wih1 packed f16 in registers (73 h2 ~= 73 VGPRs -> total ~120,
// under the 170-reg unified cap at 3 waves/SIMD, so NO spill / AGPR copies —
// round-2's VGPR_Count=84 + 69MB scratch writes showed the 105-h2 version
// spilled). Whh1 (96 KB f16) streamed from LDS via lane-consecutive
// ds_read_b128 (conflict-free; LDS pipe was idle). Partial dots combined via
// DPP quad_perm xor-1 (VALU, replaces ds_swizzle shfl). Hidden state packed
// f16 in LDS (2-addr/wave broadcast reads = free). Imputation fused in wave 0.
// 3 barriers/step.

#define BB 256
#define SS 1024
#define DD 32
#define HH 128
#define NT 768

typedef _Float16 f16;
typedef __attribute__((ext_vector_type(2))) _Float16 h2;
typedef __attribute__((ext_vector_type(8))) _Float16 h8;

union H8v { h8 v; h2 p[4]; };

__device__ inline float dot2(h2 a, h2 b, float c) {
#if __has_builtin(__builtin_amdgcn_fdot2)
    return __builtin_amdgcn_fdot2(a, b, c, false);
#else
    return c + (float)a.x * (float)b.x + (float)a.y * (float)b.y;
#endif
}

// x + (x from adjacent lane): DPP quad_perm [1,0,3,2] — pure VALU, no LDS pipe.
__device__ inline float pair_sum(float x) {
#if __has_builtin(__builtin_amdgcn_mov_dpp)
    int y = __builtin_amdgcn_mov_dpp(__float_as_int(x), 0xB1, 0xF, 0xF, true);
    return x + __int_as_float(y);
#else
    return x + __shfl_xor(x, 1);
#endif
}

__device__ inline float frcp(float x) {
#if __has_builtin(__builtin_amdgcn_rcpf)
    return __builtin_amdgcn_rcpf(x);
#else
    return 1.0f / x;
#endif
}

__device__ inline float fast_sigm(float x) {
    return frcp(1.0f + __expf(-x));
}

__device__ inline float fast_tanh(float x) {
    x = fminf(15.0f, fmaxf(-15.0f, x));
    float e = __expf(-2.0f * x);
    return (1.0f - e) * frcp(1.0f + e);
}

struct ImpState { float xprev, tprev; bool hasprev; };

// Executed by wave 0 only (tid < 64): g = tid>>1 in [0,32), half = tid&1.
__device__ inline void impute_step(int i, float xv, int tid, ImpState& st,
                                   f16* hx, const float* tb) {
    int g = tid >> 1;
    bool nanp = ((tid & 1) == 0) && (xv != xv);
    unsigned long long bal = __ballot(nanp);
    bool mask = bal != 0ull;
    if ((tid & 1) == 0) {
        float imp = mask ? st.xprev : xv;
        hx[g] = (f16)imp;
        if (!mask) st.xprev = xv;
    }
    float tcur = tb[i];
    float tdel = (i == 0) ? 0.0f : (tcur - tb[i - 1]);
    float texp = st.hasprev ? (tcur - st.tprev) : tdel;
    if (tid == 1) hx[32] = (f16)(mask ? 1.0f : 0.0f);
    if (tid == 3) hx[33] = (f16)texp;
    if (!mask) { st.hasprev = true; st.tprev = tcur; }
}

__global__ __launch_bounds__(NT, 3) void gru_fused(
    const float* __restrict__ t_in, const float* __restrict__ x_in,
    const float* __restrict__ Wih0, const float* __restrict__ Whh0,
    const float* __restrict__ bih0, const float* __restrict__ bhh0,
    const float* __restrict__ Wih1, const float* __restrict__ Whh1,
    const float* __restrict__ bih1, const float* __restrict__ bhh1,
    float* __restrict__ out)
{
    __shared__ h8 wl[8 * NT];     // Whh1 streamed: chunk q of thread tid at wl[q*NT+tid]  (96 KB)
    __shared__ float tb[SS];      // timestamps (shared across batch)           (4 KB)
    __shared__ h8 hxs[5];         // imputed input, 40 f16 (34 used: x|mask|texp)
    __shared__ h8 h0s[16];        // h0 packed f16 (128)
    __shared__ h8 h1s[16];        // h1 packed f16 (128)
    __shared__ float rz0[256];    // r,z gates layer 0
    __shared__ float rz1[256];    // r,z gates layer 1

    const int tid = threadIdx.x;
    const int g = tid >> 1;       // gate row 0..383
    const int half = tid & 1;     // K half
    const int b = blockIdx.x;

    // ---- pack this thread's half-rows: Wih0/Whh0/Wih1 -> regs, Whh1 -> LDS ----
    h2 wih0[9], whh0[32], wih1[32];
    {
        const float* p = Wih0 + g * 34;
        const int lim = 8 + half;               // half0: 8 terms (pad 9th), half1: 9
        #pragma unroll
        for (int k = 0; k < 9; k++) {
            int e = 16 * half + 2 * k;
            f16 lo = (k < lim) ? (f16)p[e]     : (f16)0.0f;
            f16 hi = (k < lim) ? (f16)p[e + 1] : (f16)0.0f;
            h2 v = {lo, hi}; wih0[k] = v;
        }
        p = Whh0 + g * HH + 64 * half;
        #pragma unroll
        for (int k = 0; k < 32; k++) { h2 v = {(f16)p[2*k], (f16)p[2*k+1]}; whh0[k] = v; }
        p = Wih1 + g * HH + 64 * half;
        #pragma unroll
        for (int k = 0; k < 32; k++) { h2 v = {(f16)p[2*k], (f16)p[2*k+1]}; wih1[k] = v; }
        p = Whh1 + g * HH + 64 * half;
        #pragma unroll
        for (int q = 0; q < 8; q++) {
            H8v w;
            #pragma unroll
            for (int i = 0; i < 4; i++) {
                h2 v = {(f16)p[8*q + 2*i], (f16)p[8*q + 2*i + 1]}; w.p[i] = v;
            }
            wl[q * NT + tid] = w.v;
        }
    }
    const float bi0 = bih0[g], bh0 = bhh0[g], bi1 = bih1[g], bh1 = bhh1[g];

    for (int i = tid; i < SS; i += NT) tb[i] = t_in[i];
    f16* hx = (f16*)hxs;
    if (tid >= 34 && tid < 40) hx[tid] = (f16)0.0f;           // pad
    if (tid < 128) { ((f16*)h0s)[tid] = (f16)0.0f; ((f16*)h1s)[tid] = (f16)0.0f; }
    float h0r = 0.0f, h1r = 0.0f;

    const float* xrow = x_in + (size_t)b * SS * DD + g;  // deref only tid<64 even
    ImpState st; st.xprev = 0.0f; st.tprev = 0.0f; st.hasprev = false;

    __syncthreads();
    if (tid < 64) {
        float xv0 = ((tid & 1) == 0) ? xrow[0] : 0.0f;
        impute_step(0, xv0, tid, st, hx, tb);
    }
    __syncthreads();

    const h2* hx2 = (const h2*)hxs;
    const h8* h08 = (const h8*)h0s;
    const h8* h18 = (const h8*)h1s;

    for (int tt = 0; tt < SS; ++tt) {
        // prefetch next x row (consumed in impute after B_b)
        float xv_n = 0.0f;
        if (tid < 64 && (tid & 1) == 0)
            xv_n = xrow[(size_t)((tt + 1 < SS) ? (tt + 1) : (SS - 1)) * DD];

        // ---- phase 1: layer-0 partial dots over this K-half ----
        float a0 = 0.0f;
        #pragma unroll
        for (int k = 0; k < 9; k++) a0 = dot2(hx2[8 * half + k], wih0[k], a0);
        float c0 = 0, c1 = 0, c2 = 0, c3 = 0;
        #pragma unroll
        for (int q = 0; q < 8; q++) {
            H8v u; u.v = h08[8 * half + q];
            c0 = dot2(u.p[0], whh0[4*q+0], c0);
            c1 = dot2(u.p[1], whh0[4*q+1], c1);
            c2 = dot2(u.p[2], whh0[4*q+2], c2);
            c3 = dot2(u.p[3], whh0[4*q+3], c3);
        }
        float ghp = (c0 + c1) + (c2 + c3);
        float gx = bi0 + pair_sum(a0);
        float gh = bh0 + pair_sum(ghp);
        if (g < 256 && half == 0) rz0[g] = fast_sigm(gx + gh);
        __syncthreads();   // B_b

        if (tid >= 512) {           // layer-0 h update (row pair owns unit j)
            int j = g - 256;
            float r = rz0[j], z = rz0[128 + j];
            float n = fast_tanh(gx + r * gh);
            h0r = (1.0f - z) * n + z * h0r;
            if (half == 0) ((f16*)h0s)[j] = (f16)h0r;
        } else if (tid < 64) {      // impute next step concurrently
            if (tt + 1 < SS) impute_step(tt + 1, xv_n, tid, st, hx, tb);
        }
        __syncthreads();   // B_c

        // ---- phase 3: gx1 over updated h0 (regs), gh1 over h1 (Whh1 from LDS) ----
        float d0 = 0, d1 = 0, d2 = 0, d3 = 0;
        #pragma unroll
        for (int q = 0; q < 8; q++) {
            H8v u; u.v = h08[8 * half + q];
            d0 = dot2(u.p[0], wih1[4*q+0], d0);
            d1 = dot2(u.p[1], wih1[4*q+1], d1);
            d2 = dot2(u.p[2], wih1[4*q+2], d2);
            d3 = dot2(u.p[3], wih1[4*q+3], d3);
        }
        float e0 = 0, e1 = 0, e2 = 0, e3 = 0;
        #pragma unroll
        for (int q = 0; q < 8; q++) {
            H8v u; u.v = h18[8 * half + q];
            H8v w; w.v = wl[q * NT + tid];
            e0 = dot2(u.p[0], w.p[0], e0);
            e1 = dot2(u.p[1], w.p[1], e1);
            e2 = dot2(u.p[2], w.p[2], e2);
            e3 = dot2(u.p[3], w.p[3], e3);
        }
        float dxp = (d0 + d1) + (d2 + d3);
        float ehp = (e0 + e1) + (e2 + e3);
        float gx1 = bi1 + pair_sum(dxp);
        float gh1 = bh1 + pair_sum(ehp);
        if (g < 256 && half == 0) rz1[g] = fast_sigm(gx1 + gh1);
        __syncthreads();   // B_d

        if (tid >= 512) {           // layer-1 h update
            int j = g - 256;
            float r = rz1[j], z = rz1[128 + j];
            float n = fast_tanh(gx1 + r * gh1);
            h1r = (1.0f - z) * n + z * h1r;
            if (half == 0) ((f16*)h1s)[j] = (f16)h1r;
        }
        // loop-around barrier elided: every LDS buffer's read phase and its
        // next write phase are separated by >=1 intervening barrier (checked
        // per-buffer: rz0/rz1/h0s/h1s/hx; wl is read-only in the loop).
    }

    if (tid >= 512 && half == 0) out[(size_t)b * HH + (g - 256)] = h1r;
}

extern "C" void kernel_launch(void* const* d_in, const int* in_sizes, int n_in,
                              void* d_out, int out_size, void* d_ws, size_t ws_size,
                              hipStream_t stream) {
    gru_fused<<<dim3(BB), dim3(NT), 0, stream>>>(
        (const float*)d_in[0], (const float*)d_in[1],
        (const float*)d_in[2], (const float*)d_in[3],
        (const float*)d_in[4], (const float*)d_in[5],
        (const float*)d_in[6], (const float*)d_in[7],
        (const float*)d_in[8], (const float*)d_in[9],
        (float*)d_out);
}

// Round 5
// 1365.299 us; speedup vs baseline: 3.6747x; 1.2343x over previous
//
#include <hip/hip_runtime.h>
#include <hip/hip_bf16.h>

// GRU-D fused scan, SGPR-broadcast edition (v2: readfirstlane-laundered
// scalar pointers — R4 failed because group-derived pointers were marked
// divergent and the "s" asm constraint got VGPRs).
// Diagnosis R3: LDS-delivery-bound (~3900 cyc/step: every h2 operand of the
// 80K MACs/step crossed the 128 B/cyc LDS pipe). Fix: h-state (wave-uniform!)
// lives in a per-block global scratch slot and is broadcast to each wave via
// s_load_dwordx16 into SGPRs; v_dot2_f32_f16 takes the SGPR operand for free.
// K-split is wave-uniform (waves 0-5 = half0 of all 384 rows, 6-11 = half1)
// so all lanes of a wave share one SGPR K-sequence. Cross-half combine via
// LDS float4 partials; dedicated updater waves (8,9 = h0 units, 10,11 = h1)
// read partials and do the gate math. 2 barriers/step.
// Coherence: vector stores are write-through to L2, drained (vmcnt 0) at
// __syncthreads; s_dcache_inv per step refreshes scalar L1 from L2.

#define BB 256
#define SS 1024
#define DD 32
#define HH 128
#define NT 768

typedef _Float16 f16;
typedef __attribute__((ext_vector_type(2))) _Float16 h2;
typedef __attribute__((ext_vector_type(16))) int i32x16;
typedef __attribute__((ext_vector_type(8))) int i32x8;

__device__ inline h2 as_h2(int x) { union { int i; h2 h; } u; u.i = x; return u.h; }

__device__ inline float dot2(h2 a, h2 b, float c) {
    return __builtin_amdgcn_fdot2(a, b, c, false);
}

// Force a (wave-uniform-by-construction) pointer into SGPRs.
__device__ inline const void* uniform_ptr(const void* p) {
    unsigned long long u = (unsigned long long)p;
    unsigned lo = __builtin_amdgcn_readfirstlane((unsigned)u);
    unsigned hi = __builtin_amdgcn_readfirstlane((unsigned)(u >> 32));
    return (const void*)(((unsigned long long)hi << 32) | (unsigned long long)lo);
}

template<int OFF>
__device__ inline i32x16 sload_x16(const void* p) {
    i32x16 r;
    asm volatile("s_load_dwordx16 %0, %1, %2" : "=s"(r) : "s"(p), "i"(OFF));
    return r;
}
template<int OFF>
__device__ inline i32x8 sload_x8(const void* p) {
    i32x8 r;
    asm volatile("s_load_dwordx8 %0, %1, %2" : "=s"(r) : "s"(p), "i"(OFF));
    return r;
}
template<int OFF>
__device__ inline int sload_x1(const void* p) {
    int r;
    asm volatile("s_load_dword %0, %1, %2" : "=s"(r) : "s"(p), "i"(OFF));
    return r;
}

__device__ inline float frcp(float x) { return __builtin_amdgcn_rcpf(x); }
__device__ inline float fast_sigm(float x) { return frcp(1.0f + __expf(-x)); }
__device__ inline float fast_tanh(float x) {
    x = fminf(15.0f, fmaxf(-15.0f, x));
    float e = __expf(-2.0f * x);
    return (1.0f - e) * frcp(1.0f + e);
}

struct ImpState { float xprev, tprev; bool hasprev; };

// Wave 0 only (all 64 lanes active). Lane l<32 owns feature l; writes go to
// the GLOBAL hx slot (consumed by s_load next iteration).
__device__ inline void impute_store(int i, float xv, int l, ImpState& st,
                                    f16* hxg, const float* tb) {
    bool nanp = (l < 32) && (xv != xv);
    unsigned long long bal = __ballot(nanp);
    bool mask = bal != 0ull;
    if (l < 32) {
        float imp = mask ? st.xprev : xv;
        hxg[l] = (f16)imp;
        if (!mask) st.xprev = xv;
    }
    float tcur = tb[i];
    float tdel = (i == 0) ? 0.0f : (tcur - tb[i - 1]);
    float texp = st.hasprev ? (tcur - st.tprev) : tdel;
    if (l == 32) hxg[32] = (f16)(mask ? 1.0f : 0.0f);
    if (l == 33) hxg[33] = (f16)texp;
    if (!mask) { st.hasprev = true; st.tprev = tcur; }
}

__global__ __launch_bounds__(NT, 3) void gru_fused(
    const float* __restrict__ t_in, const float* __restrict__ x_in,
    const float* __restrict__ Wih0, const float* __restrict__ Whh0,
    const float* __restrict__ bih0, const float* __restrict__ bhh0,
    const float* __restrict__ Wih1, const float* __restrict__ Whh1,
    const float* __restrict__ bih1, const float* __restrict__ bhh1,
    float* __restrict__ out, char* __restrict__ ws)
{
    __shared__ float tb[SS];         // timestamps (4 KB)
    __shared__ float4 pcomb[NT];     // per-thread partials {a,c,d,e} (12 KB)

    const int tid = threadIdx.x;
    const int b = blockIdx.x;
    const int group = tid >= 384;       // K-half, wave-uniform (waves 0-5 / 6-11)
    const int row = tid - 384 * group;  // gate row 0..383

    char* base = ws + (size_t)b * 1024;
    char* h0p = base;                   // h0 state, 128 f16 (256 B)
    char* h1p = base + 256;             // h1 state, 128 f16
    char* hxp = base + 512;             // imputed input, 18 dwords (72 B)

    // ---- pack this thread's half-rows into registers (f32 -> f16x2) ----
    h2 wih0[9], whh0[32], wih1[32], whh1[32];
    {
        const float* p = Wih0 + row * 34;
        const int lim = 8 + group;      // group0: 8 real pairs (+1 zero pad), group1: 9
        #pragma unroll
        for (int k = 0; k < 9; k++) {
            int e = 16 * group + 2 * k;
            f16 lo = (k < lim) ? (f16)p[e]     : (f16)0.0f;
            f16 hi = (k < lim) ? (f16)p[e + 1] : (f16)0.0f;
            h2 v = {lo, hi}; wih0[k] = v;
        }
        p = Whh0 + row * HH + 64 * group;
        #pragma unroll
        for (int k = 0; k < 32; k++) { h2 v = {(f16)p[2*k], (f16)p[2*k+1]}; whh0[k] = v; }
        p = Wih1 + row * HH + 64 * group;
        #pragma unroll
        for (int k = 0; k < 32; k++) { h2 v = {(f16)p[2*k], (f16)p[2*k+1]}; wih1[k] = v; }
        p = Whh1 + row * HH + 64 * group;
        #pragma unroll
        for (int k = 0; k < 32; k++) { h2 v = {(f16)p[2*k], (f16)p[2*k+1]}; whh1[k] = v; }
    }

    // ---- updater setup: waves 8,9 -> h0 units; waves 10,11 -> h1 units ----
    const bool isU = (tid >= 512);
    const bool isU0 = (tid >= 512 && tid < 640);
    const int j = isU0 ? (tid - 512) : (tid - 640);   // hidden unit (updaters only)
    float ubi[3], ubh[3]; float hr = 0.0f;
    if (isU) {
        const float* bi = isU0 ? bih0 : bih1;
        const float* bh = isU0 ? bhh0 : bhh1;
        #pragma unroll
        for (int q = 0; q < 3; q++) { ubi[q] = bi[j + 128*q]; ubh[q] = bh[j + 128*q]; }
    }

    // ---- prologue: tb, zero state slots, impute(0) ----
    for (int i2 = tid; i2 < SS; i2 += NT) tb[i2] = t_in[i2];
    if (tid < 64)        ((int*)h0p)[tid]       = 0;
    else if (tid < 128)  ((int*)h1p)[tid - 64]  = 0;
    else if (tid < 146)  ((int*)hxp)[tid - 128] = 0;

    const float* xrow = x_in + (size_t)b * SS * DD + tid;   // deref only tid<32
    ImpState st; st.xprev = 0.0f; st.tprev = 0.0f; st.hasprev = false;

    __syncthreads();
    if (tid < 64) {
        float xv0 = (tid < 32) ? xrow[0] : 0.0f;
        impute_store(0, xv0, tid, st, (f16*)hxp, tb);
    }
    __syncthreads();   // drain stores to L2 before first s_load

    const void* h0g  = uniform_ptr(h0p + 128 * group);   // this wave's K-half of h0
    const void* h1g  = uniform_ptr(h1p + 128 * group);
    const void* hxg8 = uniform_ptr(hxp + 32 * group);    // dwords 0..7 / 8..15
    const void* hxg1 = uniform_ptr(hxp + (group ? 64 : 32));  // dword 16 / 8

    for (int i = 0; i <= SS; ++i) {
        const bool doL0 = (i < SS), doL1 = (i > 0), doImp = (i + 1 < SS);

        // fresh h/hx from L2 into SGPRs
        asm volatile("s_dcache_inv" ::: "memory");
        i32x16 h0a = sload_x16<0>(h0g);
        i32x16 h0b = sload_x16<64>(h0g);
        i32x16 h1a = sload_x16<0>(h1g);
        i32x16 h1b = sload_x16<64>(h1g);
        i32x8  hxv = sload_x8<0>(hxg8);
        int    hxe = sload_x1<0>(hxg1);

        // prefetch next x row for imputation (overlaps SMEM latency)
        float xv_n = 0.0f;
        if (tid < 32 && doImp) xv_n = xrow[(size_t)(i + 1) * DD];

        asm volatile("s_waitcnt lgkmcnt(0)"
                     : "+s"(h0a), "+s"(h0b), "+s"(h1a), "+s"(h1b), "+s"(hxv), "+s"(hxe)
                     :: "memory");

        // ---- dots: h-operands from SGPRs (free broadcast), weights in VGPRs ----
        float aP = 0.0f;
        #pragma unroll
        for (int k = 0; k < 9; k++) {
            int d = (k < 8) ? hxv[k] : hxe;
            aP = dot2(as_h2(d), wih0[k], aP);
        }
        float cC[4] = {0,0,0,0}, dC[4] = {0,0,0,0}, eC[4] = {0,0,0,0};
        #pragma unroll
        for (int k = 0; k < 32; k++) {
            h2 hh = as_h2((k < 16) ? h0a[k] : h0b[k - 16]);
            cC[k & 3] = dot2(hh, whh0[k], cC[k & 3]);
            dC[k & 3] = dot2(hh, wih1[k], dC[k & 3]);
        }
        #pragma unroll
        for (int k = 0; k < 32; k++) {
            h2 hh = as_h2((k < 16) ? h1a[k] : h1b[k - 16]);
            eC[k & 3] = dot2(hh, whh1[k], eC[k & 3]);
        }
        float cP = (cC[0] + cC[1]) + (cC[2] + cC[3]);
        float dP = (dC[0] + dC[1]) + (dC[2] + dC[3]);
        float eP = (eC[0] + eC[1]) + (eC[2] + eC[3]);
        pcomb[tid] = make_float4(aP, cP, dP, eP);
        __syncthreads();   // B1

        // ---- update phase ----
        if (isU) {
            bool act = isU0 ? doL0 : doL1;
            if (act) {
                float4 pa0 = pcomb[j],       pb0 = pcomb[384 + j];
                float4 pa1 = pcomb[j + 128], pb1 = pcomb[384 + j + 128];
                float4 pa2 = pcomb[j + 256], pb2 = pcomb[384 + j + 256];
                float rx, rh, zx, zh, nx, nh;
                if (isU0) {   // L0: a (=.x) is gx-part, c (=.y) is gh-part
                    rx = pa0.x + pb0.x; rh = pa0.y + pb0.y;
                    zx = pa1.x + pb1.x; zh = pa1.y + pb1.y;
                    nx = pa2.x + pb2.x; nh = pa2.y + pb2.y;
                } else {      // L1: d (=.z) is gx-part, e (=.w) is gh-part
                    rx = pa0.z + pb0.z; rh = pa0.w + pb0.w;
                    zx = pa1.z + pb1.z; zh = pa1.w + pb1.w;
                    nx = pa2.z + pb2.z; nh = pa2.w + pb2.w;
                }
                float r = fast_sigm(ubi[0] + ubh[0] + rx + rh);
                float z = fast_sigm(ubi[1] + ubh[1] + zx + zh);
                float n = fast_tanh(ubi[2] + nx + r * (ubh[2] + nh));
                hr = (1.0f - z) * n + z * hr;
                f16* hp = (f16*)(isU0 ? h0p : h1p);
                hp[j] = (f16)hr;        // global f16 store, drained at B2
            }
        } else if (tid < 64 && doImp) {
            impute_store(i + 1, xv_n, tid, st, (f16*)hxp, tb);
        }
        __syncthreads();   // B2: vmcnt(0) drain -> stores visible in L2
    }

    if (tid >= 640) out[(size_t)b * HH + (tid - 640)] = hr;
}

extern "C" void kernel_launch(void* const* d_in, const int* in_sizes, int n_in,
                              void* d_out, int out_size, void* d_ws, size_t ws_size,
                              hipStream_t stream) {
    // needs 256 KB of d_ws (1 KB per block region)
    gru_fused<<<dim3(BB), dim3(NT), 0, stream>>>(
        (const float*)d_in[0], (const float*)d_in[1],
        (const float*)d_in[2], (const float*)d_in[3],
        (const float*)d_in[4], (const float*)d_in[5],
        (const float*)d_in[6], (const float*)d_in[7],
        (const float*)d_in[8], (const float*)d_in[9],
        (float*)d_out, (char*)d_ws);
}